// Round 16
// baseline (357.804 us; speedup 1.0000x reference)
//
#include <hip/hip_runtime.h>
#include <math.h>

#define N_NODES 131072
#define N_EDGES 262144
#define N_B     4096
// NODE_DIM=16, EDGE_DIM=4, HIDDEN=64, MLP_HID=128

typedef __attribute__((ext_vector_type(8))) short short8;
typedef __attribute__((ext_vector_type(8))) _Float16 half8;
typedef __attribute__((ext_vector_type(4))) float f32x4;
typedef __attribute__((ext_vector_type(16))) float f32x16;

__device__ __forceinline__ float fast_sig(float x) {
    return 1.0f / (1.0f + __expf(-x));
}
__device__ __forceinline__ float fast_tanh(float x) {
    float t = __expf(-2.0f * fabsf(x));
    float r = (1.0f - t) / (1.0f + t);
    return copysignf(r, x);
}

// async global->LDS 16B copy: per-lane global src, wave-uniform LDS base
__device__ __forceinline__ void load_lds16(const void* g, void* l) {
    __builtin_amdgcn_global_load_lds(
        (const __attribute__((address_space(1))) unsigned int*)g,
        (__attribute__((address_space(3))) unsigned int*)l, 16, 0, 0);
}

// -------- merged prep kernel: blockIdx ranges dispatch the prep jobs ------
// bids [0,64): we2 fp16 frags; [64,72): GRU weights; [72,88): LSTM packs;
// [88,105): starts binary search; [105,1129): dst-degree histogram.
__global__ __launch_bounds__(256) void k_misc(
    const float* __restrict__ we2, unsigned short* __restrict__ wt,
    const float* __restrict__ gwih, const float* __restrict__ gwhh,
    const float* __restrict__ gbih, const float* __restrict__ gbhh,
    unsigned short* __restrict__ wtg, float* __restrict__ gbias,
    const float* __restrict__ lwih, const float* __restrict__ lwhh,
    float4* __restrict__ wA, float4* __restrict__ wB,
    const int* __restrict__ batch, int* __restrict__ starts,
    const int* __restrict__ eidx, int* __restrict__ deg)
{
    const int bid = blockIdx.x;
    const int tid = threadIdx.x;
    if (bid >= 105) {
        // ---- histogram of dst degrees (deg pre-zeroed by memset) ----
        int p = (bid - 105) * 256 + tid;  // [0, 262144) == N_EDGES
        atomicAdd(&deg[eidx[N_EDGES + p]], 1);
        return;
    }
    if (bid < 64) {
        // ---- prep_w: wt[d(16)][u(2)][s(8)][lane(64)][j(8)] single fp16 ----
        int p = bid * 256 + tid;  // [0, 16384)
        int d = p >> 10;
        int u = (p >> 9) & 1;
        int s = (p >> 6) & 7;
        int l = p & 63;
        int k0 = s * 16 + ((l >> 5) << 3);
        int h = u * 32 + (l & 31);
        half8 hv;
        #pragma unroll
        for (int j = 0; j < 8; ++j) {
            float v = we2[(size_t)(k0 + j) * 1024 + d * 64 + h];
            hv[j] = (_Float16)v;   // RNE
        }
        size_t base = (size_t)d * 8192 + (size_t)u * 4096 + s * 512 + l * 8;
        *(half8*)&wt[base] = hv;
    } else if (bid < 72) {
        // ---- prep_gru: single RNE fp16 weights ----
        int p = (bid - 64) * 256 + tid;  // [0, 2048)
        if (p < 256) {
            int g = p >> 6, j = p & 63;
            float b;
            if (g == 0)      b = gbih[j] + gbhh[j];
            else if (g == 1) b = gbih[64 + j] + gbhh[64 + j];
            else if (g == 2) b = gbih[128 + j];
            else             b = gbhh[128 + j];
            gbias[p] = b;
        }
        int u = p >> 7, ks = (p >> 6) & 1, ln = p & 63;
        int n = u * 16 + (ln & 15);
        int g = n >> 6, jn = n & 63;
        int k0 = ks * 32 + (ln >> 4) * 8;
        half8 hv;
        #pragma unroll
        for (int jj = 0; jj < 8; ++jj) {
            int k = k0 + jj;
            float v;
            if (g == 0)      v = gwih[jn * 64 + k] + gwhh[jn * 64 + k];
            else if (g == 1) v = gwih[(64 + jn) * 64 + k] + gwhh[(64 + jn) * 64 + k];
            else if (g == 2) v = gwih[(128 + jn) * 64 + k];
            else             v = gwhh[(128 + jn) * 64 + k];
            hv[jj] = (_Float16)v;
        }
        size_t base = (size_t)(u * 2 + ks) * 512 + ln * 8;
        *(half8*)&wtg[base] = hv;
    } else if (bid < 88) {
        // ---- prep_lstm: wA merges wih[:, :64]+whh (q_prev==h_prev) ----
        int p = (bid - 72) * 256 + tid;  // [0, 4096)
        int k = p >> 6, ln = p & 63;
        float4 a, b;
        a.x = lwih[(0 * 64 + ln) * 128 + k] + lwhh[(0 * 64 + ln) * 64 + k];
        a.y = lwih[(1 * 64 + ln) * 128 + k] + lwhh[(1 * 64 + ln) * 64 + k];
        a.z = lwih[(2 * 64 + ln) * 128 + k] + lwhh[(2 * 64 + ln) * 64 + k];
        a.w = lwih[(3 * 64 + ln) * 128 + k] + lwhh[(3 * 64 + ln) * 64 + k];
        b.x = lwih[(0 * 64 + ln) * 128 + 64 + k];
        b.y = lwih[(1 * 64 + ln) * 128 + 64 + k];
        b.z = lwih[(2 * 64 + ln) * 128 + 64 + k];
        b.w = lwih[(3 * 64 + ln) * 128 + 64 + k];
        wA[p] = a; wB[p] = b;
    } else {
        // ---- starts ----
        int g = (bid - 88) * 256 + tid;
        if (g > N_B) return;
        if (g == N_B) { starts[N_B] = N_NODES; return; }
        int lo = 0, hi = N_NODES;
        while (lo < hi) {
            int mid = (lo + hi) >> 1;
            if (batch[mid] < g) lo = mid + 1; else hi = mid;
        }
        starts[g] = lo;
    }
}

// -------- CSR build: block sums -> scan of sums -> row_ptr -> epos --------
__global__ __launch_bounds__(256) void k_scan1(
    const int* __restrict__ deg, int* __restrict__ psum)
{
    __shared__ int sm[256];
    const int t = threadIdx.x;
    sm[t] = deg[blockIdx.x * 256 + t];
    __syncthreads();
    #pragma unroll
    for (int off = 128; off; off >>= 1) {
        if (t < off) sm[t] += sm[t + off];
        __syncthreads();
    }
    if (t == 0) psum[blockIdx.x] = sm[0];
}

__global__ __launch_bounds__(512) void k_scan2(
    const int* __restrict__ psum, int* __restrict__ psumx)
{
    __shared__ int sm[512];
    const int t = threadIdx.x;
    sm[t] = psum[t];
    __syncthreads();
    #pragma unroll
    for (int off = 1; off < 512; off <<= 1) {
        int add = (t >= off) ? sm[t - off] : 0;
        __syncthreads();
        sm[t] += add;
        __syncthreads();
    }
    psumx[t] = (t > 0) ? sm[t - 1] : 0;
}

__global__ __launch_bounds__(256) void k_scan3(
    const int* __restrict__ deg, const int* __restrict__ psumx,
    int* __restrict__ row_ptr, int* __restrict__ cursor)
{
    __shared__ int sm[256];
    const int t = threadIdx.x;
    const int i = blockIdx.x * 256 + t;
    int d = deg[i];
    sm[t] = d;
    __syncthreads();
    #pragma unroll
    for (int off = 1; off < 256; off <<= 1) {
        int add = (t >= off) ? sm[t - off] : 0;
        __syncthreads();
        sm[t] += add;
        __syncthreads();
    }
    int excl = sm[t] - d + psumx[blockIdx.x];
    row_ptr[i] = excl;
    cursor[i] = excl;
    if (i == 0) row_ptr[N_NODES] = N_EDGES;
}

// inverse permutation: epos[e] = slot of edge e in dst-sorted order
__global__ __launch_bounds__(256) void k_scat(
    const int* __restrict__ eidx, int* __restrict__ cursor,
    int* __restrict__ epos)
{
    int e = blockIdx.x * 256 + threadIdx.x;
    int dst = eidx[N_EDGES + e];
    epos[e] = atomicAdd(&cursor[dst], 1);
}

// -------- fused edge MLP + 32x32x16 MFMA message GEMM + permuted store ----
// v27: 256 edges/block, 8 waves, 2 m-tiles/wave -> each ds_read_b128 feeds
// TWO MFMAs (LDS reads per MFMA halved; the per-CU LDS pipe was the hidden
// ~90%-busy resource in R15's cycle budget). B staged once per 256 edges
// (L2 traffic halves again). Counted-vmcnt ring-3 schedule kept from v26.
// launch_bounds(512,2): 256-VGPR budget for the ~145-reg working set;
// LDS 101.5KB caps residency at 1 block/CU (8 waves) regardless.
__global__ __launch_bounds__(512, 2)
void k_edge(
    const float* __restrict__ x,     // [N,16]
    const float* __restrict__ ea,    // [E,4]
    const int*   __restrict__ eidx,  // [2,E]
    const int*   __restrict__ epos,  // [E] sorted position per edge
    const float* __restrict__ we1,   // [4,128]
    const float* __restrict__ be1,   // [128]
    const unsigned short* __restrict__ wt,  // fp16 we2 frags
    const float* __restrict__ be2,   // [1024]
    float* __restrict__ emsg)        // [E,64] dst-grouped
{
    // layout: [0,64K) sAh (prolog) -> buf1 [0,16K) + buf2 [16K,32K) (main)
    //         [64K,80.5K) sxT ; [80.5K,84.5K) sbe2 ; [84.5K,85.5K) spos ;
    //         [85.5K,101.5K) buf0
    __shared__ __attribute__((aligned(16))) char smem[103936];
    unsigned short* sAh  = (unsigned short*)smem;
    float* sxT  = (float*)(smem + 65536);    // [16][264] pad
    float* sbe2 = (float*)(smem + 82432);    // [1024]
    int*   spos = (int*)(smem + 86528);      // [256]
    // buf0 at smem+87552 (16KB)

    const int tid = threadIdx.x;
    const int w   = tid >> 6;        // wave [0,8)
    const int ln  = tid & 63;        // lane
    const int u   = w >> 2;          // n-tile half (cols u*32..u*32+31)
    const int mp  = w & 3;           // m-tile pair: tiles {2mp, 2mp+1}
    const int eb  = blockIdx.x * 256;
    const int d0  = blockIdx.x & 15;

    // ---- issue async stage of tile t0 into buf0 (hides under prolog) ----
    #pragma unroll
    for (int r = 0; r < 2; ++r) {
        int seg = r * 8 + w;       // 16 segments x 1KB cover the 16KB tile
        load_lds16(wt + (size_t)d0 * 8192 + seg * 512 + ln * 8,
                   smem + 87552 + seg * 1024);
    }

    if (tid < 256) spos[tid] = epos[eb + tid];
    #pragma unroll
    for (int v = tid; v < 1024; v += 512) sbe2[v] = be2[v];

    // ---- stage x transposed: sxT[d][e] = x[src[e]][d], 256 edges ----
    #pragma unroll
    for (int v = tid; v < 1024; v += 512) {
        int e = v >> 2, q = v & 3;
        int src = eidx[eb + e];
        float4 t4 = ((const float4*)(x + (size_t)src * 16))[q];
        sxT[(q * 4 + 0) * 264 + e] = t4.x;
        sxT[(q * 4 + 1) * 264 + e] = t4.y;
        sxT[(q * 4 + 2) * 264 + e] = t4.z;
        sxT[(q * 4 + 3) * 264 + e] = t4.w;
    }

    // ---- h1 = relu(ea @ we1 + be1), single RNE fp16; 256 edges ----
    #pragma unroll 1
    for (int i = 0; i < 8; ++i) {
        int cc = tid + i * 512;          // [0,4096): [mt(8)][s(8)][l(64)]
        int mtc = cc >> 9;
        int s  = (cc >> 6) & 7;
        int l  = cc & 63;
        int e   = mtc * 32 + (l & 31);
        int kk0 = s * 16 + ((l >> 5) << 3);
        float4 eav = *(const float4*)(ea + (size_t)(eb + e) * 4);
        float4 b0 = *(const float4*)(be1 + kk0);
        float4 b1 = *(const float4*)(be1 + kk0 + 4);
        float acc[8] = {b0.x, b0.y, b0.z, b0.w, b1.x, b1.y, b1.z, b1.w};
        #pragma unroll
        for (int a = 0; a < 4; ++a) {
            float4 wa0 = *(const float4*)(we1 + a * 128 + kk0);
            float4 wa1 = *(const float4*)(we1 + a * 128 + kk0 + 4);
            float ev = (a == 0) ? eav.x : (a == 1) ? eav.y : (a == 2) ? eav.z : eav.w;
            acc[0] += ev * wa0.x; acc[1] += ev * wa0.y;
            acc[2] += ev * wa0.z; acc[3] += ev * wa0.w;
            acc[4] += ev * wa1.x; acc[5] += ev * wa1.y;
            acc[6] += ev * wa1.z; acc[7] += ev * wa1.w;
        }
        half8 hv;
        #pragma unroll
        for (int j = 0; j < 8; ++j) {
            hv[j] = (_Float16)fmaxf(acc[j], 0.0f);
        }
        *(half8*)&sAh[cc * 8] = hv;
    }
    __syncthreads();   // full drain: A ready, t0 landed

    // ---- hoist this wave's 2 m-tiles of A fragments; pin (64 VGPR) ----
    half8 ah0[8], ah1[8];
    #pragma unroll
    for (int s = 0; s < 8; ++s) {
        ah0[s] = *(half8*)&sAh[(((mp * 2 + 0) * 8 + s) * 64 + ln) * 8];
        ah1[s] = *(half8*)&sAh[(((mp * 2 + 1) * 8 + s) * 64 + ln) * 8];
    }
    #pragma unroll
    for (int s = 0; s < 8; ++s) {
        asm volatile("" : "+v"(ah0[s]), "+v"(ah1[s]));
    }
    __syncthreads();   // all hoist reads done -> sAh region reusable as bufs

    // ---- issue stage t1 -> buf1 [0,16K) ----
    {
        int dn = (d0 + 1) & 15;
        #pragma unroll
        for (int r = 0; r < 2; ++r) {
            int seg = r * 8 + w;
            load_lds16(wt + (size_t)dn * 8192 + seg * 512 + ln * 8,
                       smem + 0 + seg * 1024);
        }
    }

    const int rbase = (ln >> 5) * 4;

    f32x16 msg0, msg1;
    #pragma unroll
    for (int r = 0; r < 16; ++r) { msg0[r] = 0.0f; msg1[r] = 0.0f; }

    // ring-3 byte offsets: t_k lives at off(k%3): {87552, 0, 16384}
    int m = 0;   // dd % 3
    #pragma unroll 1
    for (int dd = 0; dd < 16; ++dd) {
        const int d = (d0 + dd) & 15;

        // wait own t_dd loads complete (leave newest t_{dd+1} in flight)
        if (dd == 15) asm volatile("s_waitcnt vmcnt(0)" ::: "memory");
        else          asm volatile("s_waitcnt vmcnt(2)" ::: "memory");
        __builtin_amdgcn_s_barrier();      // all waves' t_dd segments landed
        __builtin_amdgcn_sched_barrier(0);

        const unsigned short* bcur =
            (const unsigned short*)(smem + (m == 0 ? 87552 : (m == 1 ? 0 : 16384)));

        float bv = sbe2[d * 64 + u * 32 + (ln & 31)];
        f32x16 c20, c21;
        #pragma unroll
        for (int r = 0; r < 16; ++r) { c20[r] = bv; c21[r] = bv; }

        #pragma unroll
        for (int s = 0; s < 8; ++s) {
            half8 bb = *(const half8*)&bcur[u * 4096 + s * 512 + ln * 8];
            c20 = __builtin_amdgcn_mfma_f32_32x32x16_f16(ah0[s], bb, c20, 0, 0, 0);
            c21 = __builtin_amdgcn_mfma_f32_32x32x16_f16(ah1[s], bb, c21, 0, 0, 0);
        }
        // epilogue: msg += x[:,d] * C_d   (C row = (r&3)+8*(r>>2)+rbase)
        #pragma unroll
        for (int q = 0; q < 4; ++q) {
            f32x4 xv0 = *(const f32x4*)&sxT[d * 264 + (mp * 2 + 0) * 32 + rbase + 8 * q];
            f32x4 xv1 = *(const f32x4*)&sxT[d * 264 + (mp * 2 + 1) * 32 + rbase + 8 * q];
            #pragma unroll
            for (int j = 0; j < 4; ++j) {
                msg0[q * 4 + j] = fmaf(xv0[j], c20[q * 4 + j], msg0[q * 4 + j]);
                msg1[q * 4 + j] = fmaf(xv1[j], c21[q * 4 + j], msg1[q * 4 + j]);
            }
        }

        // issue stage t_{dd+2} into buf[(dd+2)%3] (== buf[(dd-1)%3]; its
        // readers all passed this iteration's barrier)
        if (dd + 2 < 16) {
            int dn = (d0 + dd + 2) & 15;
            int mn = (m == 0) ? 2 : (m == 1 ? 0 : 1);   // (m+2)%3
            char* db = smem + (mn == 0 ? 87552 : (mn == 1 ? 0 : 16384));
            #pragma unroll
            for (int r = 0; r < 2; ++r) {
                int seg = r * 8 + w;
                load_lds16(wt + (size_t)dn * 8192 + seg * 512 + ln * 8,
                           db + seg * 1024);
            }
        }
        m = (m == 2) ? 0 : m + 1;
    }

    // ---- permuted store: row goes to its dst-sorted slot (256B aligned) --
    const int col = u * 32 + (ln & 31);
    #pragma unroll
    for (int r = 0; r < 16; ++r) {
        int row = (r & 3) + ((r >> 2) * 8) + rbase;
        int pos0 = spos[(mp * 2 + 0) * 32 + row];
        int pos1 = spos[(mp * 2 + 1) * 32 + row];
        emsg[(size_t)pos0 * 64 + col] = msg0[r];
        emsg[(size_t)pos1 * 64 + col] = msg1[r];
    }
}

// -------- fused CSR-contiguous gather + combine + 3-step GRU MFMA ---------
// v25: 128 nodes/block + launch_bounds(256,2) (R13-verified: no spill,
// grid supplies 4 blocks/CU).
__global__ __launch_bounds__(256, 2) void k_gru2(
    float* __restrict__ buf,        // [N,64] out: final h
    const float* __restrict__ emsg, // [E,64] dst-grouped
    const int* __restrict__ rowp,   // [N+1]
    const float* __restrict__ x,    // [N,16]
    const float* __restrict__ root, // [16,64]
    const float* __restrict__ cb,   // [64]
    const unsigned short* __restrict__ wtg,  // [16*2][512] fp16
    const float* __restrict__ gbias)         // [256]
{
    __shared__ unsigned short sAh[8192];   // [mt(8)][ks(2)][lane(64)][j(8)] 16KB
    __shared__ float sroot[1024];
    __shared__ float sbias[256];
    __shared__ float scb[64];
    const int tid = threadIdx.x;
    const int w = tid >> 6, ln = tid & 63, lq = ln >> 4, lm = ln & 15;
    const size_t nbase = (size_t)blockIdx.x * 128;

    #pragma unroll
    for (int v = tid; v < 1024; v += 256) sroot[v] = root[v];
    sbias[tid] = gbias[tid];
    if (tid < 64) scb[tid] = cb[tid];
    __syncthreads();

    // ---- initial A build: contiguous gather + combine (x@root+cb, relu) --
    #pragma unroll 2
    for (int i = 0; i < 4; ++i) {
        int cc = tid + i * 256;            // [0,1024): [mt(8)][ks(2)][l(64)]
        int mt = cc >> 7, ks = (cc >> 6) & 1, l = cc & 63;
        size_t gn = nbase + mt * 16 + (l & 15);
        int c0 = ks * 32 + (l >> 4) * 8;
        int rp0 = rowp[gn], rp1 = rowp[gn + 1];
        float ms[8] = {0.f, 0.f, 0.f, 0.f, 0.f, 0.f, 0.f, 0.f};
        for (int k = rp0; k < rp1; ++k) {
            float4 m0 = *(const float4*)(emsg + (size_t)k * 64 + c0);
            float4 m1 = *(const float4*)(emsg + (size_t)k * 64 + c0 + 4);
            ms[0] += m0.x; ms[1] += m0.y; ms[2] += m0.z; ms[3] += m0.w;
            ms[4] += m1.x; ms[5] += m1.y; ms[6] += m1.z; ms[7] += m1.w;
        }
        float cinv = 1.0f / fmaxf((float)(rp1 - rp0), 1.0f);
        float xv[16];
        *(float4*)&xv[0]  = *(const float4*)(x + gn * 16);
        *(float4*)&xv[4]  = *(const float4*)(x + gn * 16 + 4);
        *(float4*)&xv[8]  = *(const float4*)(x + gn * 16 + 8);
        *(float4*)&xv[12] = *(const float4*)(x + gn * 16 + 12);
        float acc[8];
        #pragma unroll
        for (int j = 0; j < 8; ++j) acc[j] = scb[c0 + j];
        #pragma unroll
        for (int d = 0; d < 16; ++d) {
            float xd = xv[d];
            #pragma unroll
            for (int j = 0; j < 8; ++j) acc[j] += xd * sroot[d * 64 + c0 + j];
        }
        half8 hv;
        #pragma unroll
        for (int j = 0; j < 8; ++j) {
            float hval = fmaxf(ms[j] * cinv + acc[j], 0.0f);
            hv[j] = (_Float16)hval;   // RNE single fp16
        }
        *(half8*)&sAh[cc * 8] = hv;
    }
    __syncthreads();

    #pragma unroll 1
    for (int step = 0; step < 3; ++step) {
        half8 ah[2][2];
        #pragma unroll
        for (int i = 0; i < 2; ++i)
            #pragma unroll
            for (int ks = 0; ks < 2; ++ks) {
                int mt = w * 2 + i;
                ah[i][ks] = *(half8*)&sAh[((mt * 2 + ks) * 64 + ln) * 8];
            }
        __syncthreads();   // all fragment reads done before any epilogue write

        #pragma unroll 1
        for (int v = 0; v < 4; ++v) {
            f32x4 C[4][2];  // [gate g][m-tile i]
            #pragma unroll
            for (int g = 0; g < 4; ++g) {
                float bv = sbias[g * 64 + v * 16 + lm];
                #pragma unroll
                for (int i = 0; i < 2; ++i) C[g][i] = (f32x4){bv, bv, bv, bv};
            }
            #pragma unroll
            for (int g = 0; g < 4; ++g) {
                int u = g * 4 + v;
                #pragma unroll
                for (int ks = 0; ks < 2; ++ks) {
                    size_t wb = (size_t)(u * 2 + ks) * 512 + ln * 8;
                    half8 bb = *(const half8*)&wtg[wb];
                    #pragma unroll
                    for (int i = 0; i < 2; ++i) {
                        C[g][i] = __builtin_amdgcn_mfma_f32_16x16x32_f16(ah[i][ks], bb, C[g][i], 0, 0, 0);
                    }
                }
            }
            int ksp = v >> 1;
            int lq2 = (v & 1) * 2 + (lm >> 3);
            int jp = lm & 7;
            #pragma unroll
            for (int i = 0; i < 2; ++i) {
                int mt = w * 2 + i;
                #pragma unroll
                for (int r = 0; r < 4; ++r) {
                    int idx = ((mt * 2 + ksp) * 64 + lq2 * 16 + lq * 4 + r) * 8 + jp;
                    // old h: re-read from LDS (same thread owns this idx)
                    float hold = (float)*(const _Float16*)&sAh[idx];
                    float rr = fast_sig(C[0][i][r]);
                    float zz = fast_sig(C[1][i][r]);
                    float nn = fast_tanh(C[2][i][r] + rr * C[3][i][r]);
                    float hnew = (1.0f - zz) * nn + zz * hold;
                    if (step < 2) {
                        _Float16 hh = (_Float16)hnew;
                        sAh[idx] = *(unsigned short*)&hh;
                    } else {
                        buf[(nbase + mt * 16 + lq * 4 + r) * 64 + v * 16 + lm] = hnew;
                    }
                }
            }
        }
        if (step < 2) __syncthreads();
    }
}

// -------- Set2Set (3 steps) + final MLP; wave-per-graph, 4 graphs/block ----
__global__ __launch_bounds__(256) void k_s2s(
    const float* __restrict__ out,    // [N,64]
    const int*   __restrict__ starts, // [B+1]
    const float4* __restrict__ wA,    // [64*64] packed gate weights vs h_prev
    const float4* __restrict__ wB,    // [64*64] packed gate weights vs rg_prev
    const float* __restrict__ bih,    // [256]
    const float* __restrict__ bhh,    // [256]
    const float* __restrict__ fc1w,   // [128,64]
    const float* __restrict__ fc1b,   // [64]
    const float* __restrict__ fc2w,   // [64]
    const float* __restrict__ fc2b,   // [1]
    float* __restrict__ y)            // [B]
{
    __shared__ float osh[4][32][66];  // staged rows, +2 pad  (33.8KB)
    __shared__ float qsL[4][128];     // [graph][ h(64) | r_g(64) ]
    __shared__ float ebuf[4][256];
    const int tid = threadIdx.x;
    const int wv = tid >> 6, ln = tid & 63;
    const int gid = blockIdx.x * 4 + wv;

    const int s0 = starts[gid];
    int L = starts[gid + 1] - s0; if (L > 256) L = 256;
    const int SL = (L < 32) ? L : 32;                    // staged row count

    // ---- stage first SL rows (coalesced: 16 consecutive lanes = one row) ----
    #pragma unroll
    for (int base = 0; base < 32; base += 4) {
        int row = base + (ln >> 4);
        int c4 = (ln & 15) * 4;
        if (row < SL)
            *(float4*)&osh[wv][row][c4] =
                *(const float4*)(out + (size_t)(s0 + row) * 64 + c4);
    }

    qsL[wv][ln] = 0.0f; qsL[wv][64 + ln] = 0.0f;
    __builtin_amdgcn_wave_barrier();

    const float b0 = bih[ln] + bhh[ln];
    const float b1 = bih[64 + ln] + bhh[64 + ln];
    const float b2 = bih[128 + ln] + bhh[128 + ln];
    const float b3 = bih[192 + ln] + bhh[192 + ln];

    float c = 0.0f;

    #pragma unroll 1
    for (int step = 0; step < 3; ++step) {
        // ---- gates: lane ln = rows {ln, 64+ln, 128+ln, 192+ln} ----
        float a0 = b0, a1 = b1, a2 = b2, a3 = b3;
        #pragma unroll 4
        for (int k = 0; k < 64; ++k) {
            float qk = qsL[wv][k];          // h_prev[k] (== q_prev[k])
            float rk = qsL[wv][64 + k];     // r_g prev[k]
            float4 wa = wA[k * 64 + ln];    // coalesced
            float4 wb = wB[k * 64 + ln];
            a0 += wa.x * qk + wb.x * rk;
            a1 += wa.y * qk + wb.y * rk;
            a2 += wa.z * qk + wb.z * rk;
            a3 += wa.w * qk + wb.w * rk;
        }
        float ig = fast_sig(a0), fg = fast_sig(a1);
        float gg = fast_tanh(a2), og = fast_sig(a3);
        c = fg * c + ig * gg;
        float h = og * fast_tanh(c);
        __builtin_amdgcn_wave_barrier();
        qsL[wv][ln] = h;                    // new q part (wave-private)
        __builtin_amdgcn_wave_barrier();

        // ---- attention: e_j = out[j].h ; staged rows from LDS ----
        float m = -1e30f;
        for (int c0 = 0; c0 * 64 < L; ++c0) {
            int j = c0 * 64 + ln;
            if (j < L) {
                float a = 0.0f;
                if (j < SL) {
                    #pragma unroll
                    for (int l4 = 0; l4 < 16; ++l4) {
                        float4 ov = *(const float4*)&osh[wv][j][l4 * 4];
                        float4 hv = *(const float4*)&qsL[wv][l4 * 4];
                        a += ov.x * hv.x + ov.y * hv.y + ov.z * hv.z + ov.w * hv.w;
                    }
                } else {
                    const float4* orow = (const float4*)(out + (size_t)(s0 + j) * 64);
                    #pragma unroll
                    for (int l4 = 0; l4 < 16; ++l4) {
                        float4 ov = orow[l4];
                        float4 hv = *(const float4*)&qsL[wv][l4 * 4];
                        a += ov.x * hv.x + ov.y * hv.y + ov.z * hv.z + ov.w * hv.w;
                    }
                }
                ebuf[wv][j] = a;
                m = fmaxf(m, a);
            }
        }
        #pragma unroll
        for (int off = 32; off; off >>= 1) m = fmaxf(m, __shfl_xor(m, off));
        float ds = 0.0f;
        for (int c0 = 0; c0 * 64 < L; ++c0) {
            int j = c0 * 64 + ln;
            if (j < L) {
                float ex = __expf(ebuf[wv][j] - m);
                ebuf[wv][j] = ex;
                ds += ex;
            }
        }
        #pragma unroll
        for (int off = 32; off; off >>= 1) ds += __shfl_xor(ds, off);
        __builtin_amdgcn_wave_barrier();
        // r_g[ln] = sum_j a_j * out[s0+j][ln]
        float rg = 0.0f;
        for (int j = 0; j < SL; ++j)
            rg = fmaf(ebuf[wv][j], osh[wv][j][ln], rg);
        for (int j = SL; j < L; ++j)
            rg = fmaf(ebuf[wv][j], out[(size_t)(s0 + j) * 64 + ln], rg);
        rg = (L > 0) ? (rg / ds) : 0.0f;
        qsL[wv][64 + ln] = rg;
        __builtin_amdgcn_wave_barrier();
    }

    // ---- final MLP: u = relu(q_star@fc1 + b); y = u@fc2 + b2 ----
    float a = fc1b[ln];
    #pragma unroll 4
    for (int k = 0; k < 128; ++k)
        a = fmaf(qsL[wv][k], fc1w[k * 64 + ln], a);
    float uu = fmaxf(a, 0.0f) * fc2w[ln];
    #pragma unroll
    for (int off = 32; off; off >>= 1) uu += __shfl_xor(uu, off);
    if (ln == 0) y[gid] = uu + fc2b[0];
}

extern "C" void kernel_launch(void* const* d_in, const int* in_sizes, int n_in,
                              void* d_out, int out_size, void* d_ws, size_t ws_size,
                              hipStream_t stream) {
    const float* x     = (const float*)d_in[0];
    const float* ea    = (const float*)d_in[1];
    const int*   eidx  = (const int*)d_in[2];
    const int*   batch = (const int*)d_in[3];
    const float* we1   = (const float*)d_in[4];
    const float* be1   = (const float*)d_in[5];
    const float* we2   = (const float*)d_in[6];
    const float* be2   = (const float*)d_in[7];
    const float* root  = (const float*)d_in[8];
    const float* cb    = (const float*)d_in[9];
    const float* gwih  = (const float*)d_in[10];
    const float* gwhh  = (const float*)d_in[11];
    const float* gbih  = (const float*)d_in[12];
    const float* gbhh  = (const float*)d_in[13];
    const float* lwih  = (const float*)d_in[14];
    const float* lwhh  = (const float*)d_in[15];
    const float* lbih  = (const float*)d_in[16];
    const float* lbhh  = (const float*)d_in[17];
    const float* fc1w  = (const float*)d_in[18];
    const float* fc1b  = (const float*)d_in[19];
    const float* fc2w  = (const float*)d_in[20];
    const float* fc2b  = (const float*)d_in[21];

    float* emsg = (float*)d_ws;                          // [E,64] 67MB
    float* buf  = emsg + (size_t)N_EDGES * 64;           // [N,64] 33.5MB
    int* deg    = (int*)(buf + (size_t)N_NODES * 64);    // [N]
    int* cursor = deg + N_NODES;                          // [N]
    int* rowp   = cursor + N_NODES;                       // [N+1]
    int* epos   = rowp + N_NODES + 1;                     // [E]
    int* psum   = epos + N_EDGES;                         // [512]
    int* psumx  = psum + 512;                             // [512]
    int* starts = psumx + 512;                            // [B+1]
    size_t off = (size_t)((char*)(starts + N_B + 1) - (char*)d_ws);
    off = (off + 15) & ~(size_t)15;
    unsigned short* wt  = (unsigned short*)((char*)d_ws + off);  // fp16 we2 frags
    unsigned short* wtg = wt + 262144;                            // GRU fp16 frags
    float* gbias = (float*)(wtg + 32768);                         // 256 floats
    float4* wA = (float4*)(gbias + 256);                          // 64KB
    float4* wB = wA + 4096;                                       // 64KB
    float* y = (float*)d_out;

    hipMemsetAsync(deg, 0, (size_t)N_NODES * sizeof(int), stream);
    k_misc<<<1129, 256, 0, stream>>>(we2, wt, gwih, gwhh, gbih, gbhh, wtg, gbias,
                                     lwih, lwhh, wA, wB, batch, starts, eidx, deg);
    k_scan1<<<512, 256, 0, stream>>>(deg, psum);
    k_scan2<<<1, 512, 0, stream>>>(psum, psumx);
    k_scan3<<<512, 256, 0, stream>>>(deg, psumx, rowp, cursor);
    k_scat<<<1024, 256, 0, stream>>>(eidx, cursor, epos);
    k_edge<<<N_EDGES / 256, 512, 0, stream>>>(x, ea, eidx, epos, we1, be1, wt, be2, emsg);
    k_gru2<<<N_NODES / 128, 256, 0, stream>>>(buf, emsg, rowp, x, root, cb,
                                              wtg, gbias);
    k_s2s<<<N_B / 4, 256, 0, stream>>>(buf, starts, wA, wB, lbih, lbhh,
                                       fc1w, fc1b, fc2w, fc2b, y);
}

// Round 17
// 349.656 us; speedup vs baseline: 1.0233x; 1.0233x over previous
//
#include <hip/hip_runtime.h>
#include <math.h>

#define N_NODES 131072
#define N_EDGES 262144
#define N_B     4096
// NODE_DIM=16, EDGE_DIM=4, HIDDEN=64, MLP_HID=128

typedef __attribute__((ext_vector_type(8))) short short8;
typedef __attribute__((ext_vector_type(8))) _Float16 half8;
typedef __attribute__((ext_vector_type(4))) float f32x4;
typedef __attribute__((ext_vector_type(16))) float f32x16;

__device__ __forceinline__ float fast_sig(float x) {
    return 1.0f / (1.0f + __expf(-x));
}
__device__ __forceinline__ float fast_tanh(float x) {
    float t = __expf(-2.0f * fabsf(x));
    float r = (1.0f - t) / (1.0f + t);
    return copysignf(r, x);
}

// async global->LDS 16B copy: per-lane global src, wave-uniform LDS base
__device__ __forceinline__ void load_lds16(const void* g, void* l) {
    __builtin_amdgcn_global_load_lds(
        (const __attribute__((address_space(1))) unsigned int*)g,
        (__attribute__((address_space(3))) unsigned int*)l, 16, 0, 0);
}

// -------- merged prep kernel: blockIdx ranges dispatch the prep jobs ------
// bids [0,64): we2 fp16 frags; [64,72): GRU weights; [72,88): LSTM packs;
// [88,105): starts binary search; [105,1129): dst-degree histogram.
__global__ __launch_bounds__(256) void k_misc(
    const float* __restrict__ we2, unsigned short* __restrict__ wt,
    const float* __restrict__ gwih, const float* __restrict__ gwhh,
    const float* __restrict__ gbih, const float* __restrict__ gbhh,
    unsigned short* __restrict__ wtg, float* __restrict__ gbias,
    const float* __restrict__ lwih, const float* __restrict__ lwhh,
    float4* __restrict__ wA, float4* __restrict__ wB,
    const int* __restrict__ batch, int* __restrict__ starts,
    const int* __restrict__ eidx, int* __restrict__ deg)
{
    const int bid = blockIdx.x;
    const int tid = threadIdx.x;
    if (bid >= 105) {
        // ---- histogram of dst degrees (deg pre-zeroed by memset) ----
        int p = (bid - 105) * 256 + tid;  // [0, 262144) == N_EDGES
        atomicAdd(&deg[eidx[N_EDGES + p]], 1);
        return;
    }
    if (bid < 64) {
        // ---- prep_w: wt[d(16)][u(2)][s(8)][lane(64)][j(8)] single fp16 ----
        int p = bid * 256 + tid;  // [0, 16384)
        int d = p >> 10;
        int u = (p >> 9) & 1;
        int s = (p >> 6) & 7;
        int l = p & 63;
        int k0 = s * 16 + ((l >> 5) << 3);
        int h = u * 32 + (l & 31);
        half8 hv;
        #pragma unroll
        for (int j = 0; j < 8; ++j) {
            float v = we2[(size_t)(k0 + j) * 1024 + d * 64 + h];
            hv[j] = (_Float16)v;   // RNE
        }
        size_t base = (size_t)d * 8192 + (size_t)u * 4096 + s * 512 + l * 8;
        *(half8*)&wt[base] = hv;
    } else if (bid < 72) {
        // ---- prep_gru: single RNE fp16 weights ----
        int p = (bid - 64) * 256 + tid;  // [0, 2048)
        if (p < 256) {
            int g = p >> 6, j = p & 63;
            float b;
            if (g == 0)      b = gbih[j] + gbhh[j];
            else if (g == 1) b = gbih[64 + j] + gbhh[64 + j];
            else if (g == 2) b = gbih[128 + j];
            else             b = gbhh[128 + j];
            gbias[p] = b;
        }
        int u = p >> 7, ks = (p >> 6) & 1, ln = p & 63;
        int n = u * 16 + (ln & 15);
        int g = n >> 6, jn = n & 63;
        int k0 = ks * 32 + (ln >> 4) * 8;
        half8 hv;
        #pragma unroll
        for (int jj = 0; jj < 8; ++jj) {
            int k = k0 + jj;
            float v;
            if (g == 0)      v = gwih[jn * 64 + k] + gwhh[jn * 64 + k];
            else if (g == 1) v = gwih[(64 + jn) * 64 + k] + gwhh[(64 + jn) * 64 + k];
            else if (g == 2) v = gwih[(128 + jn) * 64 + k];
            else             v = gwhh[(128 + jn) * 64 + k];
            hv[jj] = (_Float16)v;
        }
        size_t base = (size_t)(u * 2 + ks) * 512 + ln * 8;
        *(half8*)&wtg[base] = hv;
    } else if (bid < 88) {
        // ---- prep_lstm: wA merges wih[:, :64]+whh (q_prev==h_prev) ----
        int p = (bid - 72) * 256 + tid;  // [0, 4096)
        int k = p >> 6, ln = p & 63;
        float4 a, b;
        a.x = lwih[(0 * 64 + ln) * 128 + k] + lwhh[(0 * 64 + ln) * 64 + k];
        a.y = lwih[(1 * 64 + ln) * 128 + k] + lwhh[(1 * 64 + ln) * 64 + k];
        a.z = lwih[(2 * 64 + ln) * 128 + k] + lwhh[(2 * 64 + ln) * 64 + k];
        a.w = lwih[(3 * 64 + ln) * 128 + k] + lwhh[(3 * 64 + ln) * 64 + k];
        b.x = lwih[(0 * 64 + ln) * 128 + 64 + k];
        b.y = lwih[(1 * 64 + ln) * 128 + 64 + k];
        b.z = lwih[(2 * 64 + ln) * 128 + 64 + k];
        b.w = lwih[(3 * 64 + ln) * 128 + 64 + k];
        wA[p] = a; wB[p] = b;
    } else {
        // ---- starts ----
        int g = (bid - 88) * 256 + tid;
        if (g > N_B) return;
        if (g == N_B) { starts[N_B] = N_NODES; return; }
        int lo = 0, hi = N_NODES;
        while (lo < hi) {
            int mid = (lo + hi) >> 1;
            if (batch[mid] < g) lo = mid + 1; else hi = mid;
        }
        starts[g] = lo;
    }
}

// -------- CSR build: block sums -> scan of sums -> row_ptr -> epos --------
__global__ __launch_bounds__(256) void k_scan1(
    const int* __restrict__ deg, int* __restrict__ psum)
{
    __shared__ int sm[256];
    const int t = threadIdx.x;
    sm[t] = deg[blockIdx.x * 256 + t];
    __syncthreads();
    #pragma unroll
    for (int off = 128; off; off >>= 1) {
        if (t < off) sm[t] += sm[t + off];
        __syncthreads();
    }
    if (t == 0) psum[blockIdx.x] = sm[0];
}

__global__ __launch_bounds__(512) void k_scan2(
    const int* __restrict__ psum, int* __restrict__ psumx)
{
    __shared__ int sm[512];
    const int t = threadIdx.x;
    sm[t] = psum[t];
    __syncthreads();
    #pragma unroll
    for (int off = 1; off < 512; off <<= 1) {
        int add = (t >= off) ? sm[t - off] : 0;
        __syncthreads();
        sm[t] += add;
        __syncthreads();
    }
    psumx[t] = (t > 0) ? sm[t - 1] : 0;
}

__global__ __launch_bounds__(256) void k_scan3(
    const int* __restrict__ deg, const int* __restrict__ psumx,
    int* __restrict__ row_ptr, int* __restrict__ cursor)
{
    __shared__ int sm[256];
    const int t = threadIdx.x;
    const int i = blockIdx.x * 256 + t;
    int d = deg[i];
    sm[t] = d;
    __syncthreads();
    #pragma unroll
    for (int off = 1; off < 256; off <<= 1) {
        int add = (t >= off) ? sm[t - off] : 0;
        __syncthreads();
        sm[t] += add;
        __syncthreads();
    }
    int excl = sm[t] - d + psumx[blockIdx.x];
    row_ptr[i] = excl;
    cursor[i] = excl;
    if (i == 0) row_ptr[N_NODES] = N_EDGES;
}

// inverse permutation: epos[e] = slot of edge e in dst-sorted order
__global__ __launch_bounds__(256) void k_scat(
    const int* __restrict__ eidx, int* __restrict__ cursor,
    int* __restrict__ epos)
{
    int e = blockIdx.x * 256 + threadIdx.x;
    int dst = eidx[N_EDGES + e];
    epos[e] = atomicAdd(&cursor[dst], 1);
}

// -------- fused edge MLP + 32x32x16 MFMA message GEMM + permuted store ----
// v28: v26 structure (128 edges, counted-vmcnt ring-3, measured-best 90us)
// + fp16 emsg store (WRITE 65.5->33MB; k_gru2 read halves; same precision
// class as the validated single-fp16 h ladder).
__global__ __launch_bounds__(512)
__attribute__((amdgpu_waves_per_eu(4, 8)))
void k_edge(
    const float* __restrict__ x,     // [N,16]
    const float* __restrict__ ea,    // [E,4]
    const int*   __restrict__ eidx,  // [2,E]
    const int*   __restrict__ epos,  // [E] sorted position per edge
    const float* __restrict__ we1,   // [4,128]
    const float* __restrict__ be1,   // [128]
    const unsigned short* __restrict__ wt,  // fp16 we2 frags
    const float* __restrict__ be2,   // [1024]
    unsigned short* __restrict__ emsg)      // [E,64] fp16, dst-grouped
{
    // layout: [0,32K) sAh (prolog) -> buf1 [0,16K) + buf2 [16K,32K) (main)
    //         [32K,48K) buf0 ; [48K..) sxT, sbe2, spos
    __shared__ __attribute__((aligned(16))) char smem[62464];
    unsigned short* sAh  = (unsigned short*)smem;
    float* sxT  = (float*)(smem + 49152);
    float* sbe2 = (float*)(smem + 57856);
    int*   spos = (int*)(smem + 61952);

    const int tid = threadIdx.x;
    const int w   = tid >> 6;        // wave [0,8)
    const int ln  = tid & 63;        // lane
    const int u   = w >> 2;          // n-tile (cols u*32..u*32+31)
    const int mt  = w & 3;           // this wave's single m-tile
    const int eb  = blockIdx.x * 128;
    const int d0  = blockIdx.x & 15;

    // ---- issue async stage of tile t0 into buf0 (hides under prolog) ----
    #pragma unroll
    for (int r = 0; r < 2; ++r) {
        int seg = r * 8 + w;       // 16 segments x 1KB cover the 16KB tile
        load_lds16(wt + (size_t)d0 * 8192 + seg * 512 + ln * 8,
                   smem + 32768 + seg * 1024);
    }

    if (tid < 128) spos[tid] = epos[eb + tid];
    #pragma unroll
    for (int v = tid; v < 1024; v += 512) sbe2[v] = be2[v];

    // ---- stage x transposed: sxT[d][e] = x[src[e]][d] ----
    {
        int e = tid >> 2, q = tid & 3;
        int src = eidx[eb + e];
        float4 t4 = ((const float4*)(x + (size_t)src * 16))[q];
        sxT[(q * 4 + 0) * 136 + e] = t4.x;
        sxT[(q * 4 + 1) * 136 + e] = t4.y;
        sxT[(q * 4 + 2) * 136 + e] = t4.z;
        sxT[(q * 4 + 3) * 136 + e] = t4.w;
    }

    // ---- h1 = relu(ea @ we1 + be1), single RNE fp16 ----
    #pragma unroll 1
    for (int i = 0; i < 4; ++i) {
        int cc = tid + i * 512;          // [0,2048): [mt(4)][s(8)][l(64)]
        int mtc = cc >> 9;
        int s  = (cc >> 6) & 7;
        int l  = cc & 63;
        int e   = mtc * 32 + (l & 31);
        int kk0 = s * 16 + ((l >> 5) << 3);
        float4 eav = *(const float4*)(ea + (size_t)(eb + e) * 4);
        float4 b0 = *(const float4*)(be1 + kk0);
        float4 b1 = *(const float4*)(be1 + kk0 + 4);
        float acc[8] = {b0.x, b0.y, b0.z, b0.w, b1.x, b1.y, b1.z, b1.w};
        #pragma unroll
        for (int a = 0; a < 4; ++a) {
            float4 wa0 = *(const float4*)(we1 + a * 128 + kk0);
            float4 wa1 = *(const float4*)(we1 + a * 128 + kk0 + 4);
            float ev = (a == 0) ? eav.x : (a == 1) ? eav.y : (a == 2) ? eav.z : eav.w;
            acc[0] += ev * wa0.x; acc[1] += ev * wa0.y;
            acc[2] += ev * wa0.z; acc[3] += ev * wa0.w;
            acc[4] += ev * wa1.x; acc[5] += ev * wa1.y;
            acc[6] += ev * wa1.z; acc[7] += ev * wa1.w;
        }
        half8 hv;
        #pragma unroll
        for (int j = 0; j < 8; ++j) {
            hv[j] = (_Float16)fmaxf(acc[j], 0.0f);
        }
        *(half8*)&sAh[cc * 8] = hv;
    }
    __syncthreads();   // full drain: A ready, t0 landed

    // ---- hoist this wave's A fragments; pin in VGPRs (32 regs) ----
    half8 ah[8];
    #pragma unroll
    for (int s = 0; s < 8; ++s) {
        ah[s] = *(half8*)&sAh[((mt * 8 + s) * 64 + ln) * 8];
    }
    #pragma unroll
    for (int s = 0; s < 8; ++s) {
        asm volatile("" : "+v"(ah[s]));
    }
    __syncthreads();   // all hoist reads done -> sAh region reusable as bufs

    // ---- issue stage t1 -> buf1 [0,16K) ----
    {
        int dn = (d0 + 1) & 15;
        #pragma unroll
        for (int r = 0; r < 2; ++r) {
            int seg = r * 8 + w;
            load_lds16(wt + (size_t)dn * 8192 + seg * 512 + ln * 8,
                       smem + 0 + seg * 1024);
        }
    }

    const int rbase = (ln >> 5) * 4;

    f32x16 msg;
    #pragma unroll
    for (int r = 0; r < 16; ++r) msg[r] = 0.0f;

    // ring-3 byte offsets: t_k lives at off(k%3): {32768, 0, 16384}
    int m = 0;   // dd % 3
    #pragma unroll 1
    for (int dd = 0; dd < 16; ++dd) {
        const int d = (d0 + dd) & 15;

        // wait own t_dd loads complete (leave newest t_{dd+1} in flight)
        if (dd == 15) asm volatile("s_waitcnt vmcnt(0)" ::: "memory");
        else          asm volatile("s_waitcnt vmcnt(2)" ::: "memory");
        __builtin_amdgcn_s_barrier();      // all waves' t_dd segments landed
        __builtin_amdgcn_sched_barrier(0);

        const unsigned short* bcur =
            (const unsigned short*)(smem + (m == 0 ? 32768 : (m == 1 ? 0 : 16384)));

        float bv = sbe2[d * 64 + u * 32 + (ln & 31)];
        f32x16 c2;
        #pragma unroll
        for (int r = 0; r < 16; ++r) c2[r] = bv;

        #pragma unroll
        for (int s = 0; s < 8; ++s) {
            half8 bb = *(const half8*)&bcur[u * 4096 + s * 512 + ln * 8];
            c2 = __builtin_amdgcn_mfma_f32_32x32x16_f16(ah[s], bb, c2, 0, 0, 0);
        }
        // epilogue: msg += x[:,d] * C_d   (C row = (r&3)+8*(r>>2)+rbase)
        #pragma unroll
        for (int q = 0; q < 4; ++q) {
            f32x4 xv = *(const f32x4*)&sxT[d * 136 + mt * 32 + rbase + 8 * q];
            #pragma unroll
            for (int j = 0; j < 4; ++j) {
                msg[q * 4 + j] = fmaf(xv[j], c2[q * 4 + j], msg[q * 4 + j]);
            }
        }

        // issue stage t_{dd+2} into buf[(dd+2)%3] (== buf[(dd-1)%3]; its
        // readers all passed this iteration's barrier)
        if (dd + 2 < 16) {
            int dn = (d0 + dd + 2) & 15;
            int mn = (m == 0) ? 2 : (m == 1 ? 0 : 1);   // (m+2)%3
            char* db = smem + (mn == 0 ? 32768 : (mn == 1 ? 0 : 16384));
            #pragma unroll
            for (int r = 0; r < 2; ++r) {
                int seg = r * 8 + w;
                load_lds16(wt + (size_t)dn * 8192 + seg * 512 + ln * 8,
                           db + seg * 1024);
            }
        }
        m = (m == 2) ? 0 : m + 1;
    }

    // ---- permuted fp16 store: row goes to its dst-sorted slot ----
    const int col = u * 32 + (ln & 31);
    #pragma unroll
    for (int r = 0; r < 16; ++r) {
        int row = (r & 3) + ((r >> 2) * 8) + rbase;
        int pos = spos[mt * 32 + row];
        _Float16 hm = (_Float16)msg[r];
        emsg[(size_t)pos * 64 + col] = *(unsigned short*)&hm;
    }
}

// -------- fused CSR-contiguous gather + combine + 3-step GRU MFMA ---------
// v28: emsg is fp16 -> gather is one half8 (16B) load per edge row-slice.
// 128 nodes/block + launch_bounds(256,2) (R13-verified: no spill).
__global__ __launch_bounds__(256, 2) void k_gru2(
    float* __restrict__ buf,        // [N,64] out: final h
    const unsigned short* __restrict__ emsg, // [E,64] fp16, dst-grouped
    const int* __restrict__ rowp,   // [N+1]
    const float* __restrict__ x,    // [N,16]
    const float* __restrict__ root, // [16,64]
    const float* __restrict__ cb,   // [64]
    const unsigned short* __restrict__ wtg,  // [16*2][512] fp16
    const float* __restrict__ gbias)         // [256]
{
    __shared__ unsigned short sAh[8192];   // [mt(8)][ks(2)][lane(64)][j(8)] 16KB
    __shared__ float sroot[1024];
    __shared__ float sbias[256];
    __shared__ float scb[64];
    const int tid = threadIdx.x;
    const int w = tid >> 6, ln = tid & 63, lq = ln >> 4, lm = ln & 15;
    const size_t nbase = (size_t)blockIdx.x * 128;

    #pragma unroll
    for (int v = tid; v < 1024; v += 256) sroot[v] = root[v];
    sbias[tid] = gbias[tid];
    if (tid < 64) scb[tid] = cb[tid];
    __syncthreads();

    // ---- initial A build: contiguous gather + combine (x@root+cb, relu) --
    #pragma unroll 2
    for (int i = 0; i < 4; ++i) {
        int cc = tid + i * 256;            // [0,1024): [mt(8)][ks(2)][l(64)]
        int mt = cc >> 7, ks = (cc >> 6) & 1, l = cc & 63;
        size_t gn = nbase + mt * 16 + (l & 15);
        int c0 = ks * 32 + (l >> 4) * 8;
        int rp0 = rowp[gn], rp1 = rowp[gn + 1];
        float ms[8] = {0.f, 0.f, 0.f, 0.f, 0.f, 0.f, 0.f, 0.f};
        for (int k = rp0; k < rp1; ++k) {
            half8 mv = *(const half8*)(emsg + (size_t)k * 64 + c0);
            #pragma unroll
            for (int j = 0; j < 8; ++j) ms[j] += (float)mv[j];
        }
        float cinv = 1.0f / fmaxf((float)(rp1 - rp0), 1.0f);
        float xv[16];
        *(float4*)&xv[0]  = *(const float4*)(x + gn * 16);
        *(float4*)&xv[4]  = *(const float4*)(x + gn * 16 + 4);
        *(float4*)&xv[8]  = *(const float4*)(x + gn * 16 + 8);
        *(float4*)&xv[12] = *(const float4*)(x + gn * 16 + 12);
        float acc[8];
        #pragma unroll
        for (int j = 0; j < 8; ++j) acc[j] = scb[c0 + j];
        #pragma unroll
        for (int d = 0; d < 16; ++d) {
            float xd = xv[d];
            #pragma unroll
            for (int j = 0; j < 8; ++j) acc[j] += xd * sroot[d * 64 + c0 + j];
        }
        half8 hv;
        #pragma unroll
        for (int j = 0; j < 8; ++j) {
            float hval = fmaxf(ms[j] * cinv + acc[j], 0.0f);
            hv[j] = (_Float16)hval;   // RNE single fp16
        }
        *(half8*)&sAh[cc * 8] = hv;
    }
    __syncthreads();

    #pragma unroll 1
    for (int step = 0; step < 3; ++step) {
        half8 ah[2][2];
        #pragma unroll
        for (int i = 0; i < 2; ++i)
            #pragma unroll
            for (int ks = 0; ks < 2; ++ks) {
                int mt = w * 2 + i;
                ah[i][ks] = *(half8*)&sAh[((mt * 2 + ks) * 64 + ln) * 8];
            }
        __syncthreads();   // all fragment reads done before any epilogue write

        #pragma unroll 1
        for (int v = 0; v < 4; ++v) {
            f32x4 C[4][2];  // [gate g][m-tile i]
            #pragma unroll
            for (int g = 0; g < 4; ++g) {
                float bv = sbias[g * 64 + v * 16 + lm];
                #pragma unroll
                for (int i = 0; i < 2; ++i) C[g][i] = (f32x4){bv, bv, bv, bv};
            }
            #pragma unroll
            for (int g = 0; g < 4; ++g) {
                int u = g * 4 + v;
                #pragma unroll
                for (int ks = 0; ks < 2; ++ks) {
                    size_t wb = (size_t)(u * 2 + ks) * 512 + ln * 8;
                    half8 bb = *(const half8*)&wtg[wb];
                    #pragma unroll
                    for (int i = 0; i < 2; ++i) {
                        C[g][i] = __builtin_amdgcn_mfma_f32_16x16x32_f16(ah[i][ks], bb, C[g][i], 0, 0, 0);
                    }
                }
            }
            int ksp = v >> 1;
            int lq2 = (v & 1) * 2 + (lm >> 3);
            int jp = lm & 7;
            #pragma unroll
            for (int i = 0; i < 2; ++i) {
                int mt = w * 2 + i;
                #pragma unroll
                for (int r = 0; r < 4; ++r) {
                    int idx = ((mt * 2 + ksp) * 64 + lq2 * 16 + lq * 4 + r) * 8 + jp;
                    // old h: re-read from LDS (same thread owns this idx)
                    float hold = (float)*(const _Float16*)&sAh[idx];
                    float rr = fast_sig(C[0][i][r]);
                    float zz = fast_sig(C[1][i][r]);
                    float nn = fast_tanh(C[2][i][r] + rr * C[3][i][r]);
                    float hnew = (1.0f - zz) * nn + zz * hold;
                    if (step < 2) {
                        _Float16 hh = (_Float16)hnew;
                        sAh[idx] = *(unsigned short*)&hh;
                    } else {
                        buf[(nbase + mt * 16 + lq * 4 + r) * 64 + v * 16 + lm] = hnew;
                    }
                }
            }
        }
        if (step < 2) __syncthreads();
    }
}

// -------- Set2Set (3 steps) + final MLP; wave-per-graph, 4 graphs/block ----
__global__ __launch_bounds__(256) void k_s2s(
    const float* __restrict__ out,    // [N,64]
    const int*   __restrict__ starts, // [B+1]
    const float4* __restrict__ wA,    // [64*64] packed gate weights vs h_prev
    const float4* __restrict__ wB,    // [64*64] packed gate weights vs rg_prev
    const float* __restrict__ bih,    // [256]
    const float* __restrict__ bhh,    // [256]
    const float* __restrict__ fc1w,   // [128,64]
    const float* __restrict__ fc1b,   // [64]
    const float* __restrict__ fc2w,   // [64]
    const float* __restrict__ fc2b,   // [1]
    float* __restrict__ y)            // [B]
{
    __shared__ float osh[4][32][66];  // staged rows, +2 pad  (33.8KB)
    __shared__ float qsL[4][128];     // [graph][ h(64) | r_g(64) ]
    __shared__ float ebuf[4][256];
    const int tid = threadIdx.x;
    const int wv = tid >> 6, ln = tid & 63;
    const int gid = blockIdx.x * 4 + wv;

    const int s0 = starts[gid];
    int L = starts[gid + 1] - s0; if (L > 256) L = 256;
    const int SL = (L < 32) ? L : 32;                    // staged row count

    // ---- stage first SL rows (coalesced: 16 consecutive lanes = one row) ----
    #pragma unroll
    for (int base = 0; base < 32; base += 4) {
        int row = base + (ln >> 4);
        int c4 = (ln & 15) * 4;
        if (row < SL)
            *(float4*)&osh[wv][row][c4] =
                *(const float4*)(out + (size_t)(s0 + row) * 64 + c4);
    }

    qsL[wv][ln] = 0.0f; qsL[wv][64 + ln] = 0.0f;
    __builtin_amdgcn_wave_barrier();

    const float b0 = bih[ln] + bhh[ln];
    const float b1 = bih[64 + ln] + bhh[64 + ln];
    const float b2 = bih[128 + ln] + bhh[128 + ln];
    const float b3 = bih[192 + ln] + bhh[192 + ln];

    float c = 0.0f;

    #pragma unroll 1
    for (int step = 0; step < 3; ++step) {
        // ---- gates: lane ln = rows {ln, 64+ln, 128+ln, 192+ln} ----
        float a0 = b0, a1 = b1, a2 = b2, a3 = b3;
        #pragma unroll 4
        for (int k = 0; k < 64; ++k) {
            float qk = qsL[wv][k];          // h_prev[k] (== q_prev[k])
            float rk = qsL[wv][64 + k];     // r_g prev[k]
            float4 wa = wA[k * 64 + ln];    // coalesced
            float4 wb = wB[k * 64 + ln];
            a0 += wa.x * qk + wb.x * rk;
            a1 += wa.y * qk + wb.y * rk;
            a2 += wa.z * qk + wb.z * rk;
            a3 += wa.w * qk + wb.w * rk;
        }
        float ig = fast_sig(a0), fg = fast_sig(a1);
        float gg = fast_tanh(a2), og = fast_sig(a3);
        c = fg * c + ig * gg;
        float h = og * fast_tanh(c);
        __builtin_amdgcn_wave_barrier();
        qsL[wv][ln] = h;                    // new q part (wave-private)
        __builtin_amdgcn_wave_barrier();

        // ---- attention: e_j = out[j].h ; staged rows from LDS ----
        float m = -1e30f;
        for (int c0 = 0; c0 * 64 < L; ++c0) {
            int j = c0 * 64 + ln;
            if (j < L) {
                float a = 0.0f;
                if (j < SL) {
                    #pragma unroll
                    for (int l4 = 0; l4 < 16; ++l4) {
                        float4 ov = *(const float4*)&osh[wv][j][l4 * 4];
                        float4 hv = *(const float4*)&qsL[wv][l4 * 4];
                        a += ov.x * hv.x + ov.y * hv.y + ov.z * hv.z + ov.w * hv.w;
                    }
                } else {
                    const float4* orow = (const float4*)(out + (size_t)(s0 + j) * 64);
                    #pragma unroll
                    for (int l4 = 0; l4 < 16; ++l4) {
                        float4 ov = orow[l4];
                        float4 hv = *(const float4*)&qsL[wv][l4 * 4];
                        a += ov.x * hv.x + ov.y * hv.y + ov.z * hv.z + ov.w * hv.w;
                    }
                }
                ebuf[wv][j] = a;
                m = fmaxf(m, a);
            }
        }
        #pragma unroll
        for (int off = 32; off; off >>= 1) m = fmaxf(m, __shfl_xor(m, off));
        float ds = 0.0f;
        for (int c0 = 0; c0 * 64 < L; ++c0) {
            int j = c0 * 64 + ln;
            if (j < L) {
                float ex = __expf(ebuf[wv][j] - m);
                ebuf[wv][j] = ex;
                ds += ex;
            }
        }
        #pragma unroll
        for (int off = 32; off; off >>= 1) ds += __shfl_xor(ds, off);
        __builtin_amdgcn_wave_barrier();
        // r_g[ln] = sum_j a_j * out[s0+j][ln]
        float rg = 0.0f;
        for (int j = 0; j < SL; ++j)
            rg = fmaf(ebuf[wv][j], osh[wv][j][ln], rg);
        for (int j = SL; j < L; ++j)
            rg = fmaf(ebuf[wv][j], out[(size_t)(s0 + j) * 64 + ln], rg);
        rg = (L > 0) ? (rg / ds) : 0.0f;
        qsL[wv][64 + ln] = rg;
        __builtin_amdgcn_wave_barrier();
    }

    // ---- final MLP: u = relu(q_star@fc1 + b); y = u@fc2 + b2 ----
    float a = fc1b[ln];
    #pragma unroll 4
    for (int k = 0; k < 128; ++k)
        a = fmaf(qsL[wv][k], fc1w[k * 64 + ln], a);
    float uu = fmaxf(a, 0.0f) * fc2w[ln];
    #pragma unroll
    for (int off = 32; off; off >>= 1) uu += __shfl_xor(uu, off);
    if (ln == 0) y[gid] = uu + fc2b[0];
}

extern "C" void kernel_launch(void* const* d_in, const int* in_sizes, int n_in,
                              void* d_out, int out_size, void* d_ws, size_t ws_size,
                              hipStream_t stream) {
    const float* x     = (const float*)d_in[0];
    const float* ea    = (const float*)d_in[1];
    const int*   eidx  = (const int*)d_in[2];
    const int*   batch = (const int*)d_in[3];
    const float* we1   = (const float*)d_in[4];
    const float* be1   = (const float*)d_in[5];
    const float* we2   = (const float*)d_in[6];
    const float* be2   = (const float*)d_in[7];
    const float* root  = (const float*)d_in[8];
    const float* cb    = (const float*)d_in[9];
    const float* gwih  = (const float*)d_in[10];
    const float* gwhh  = (const float*)d_in[11];
    const float* gbih  = (const float*)d_in[12];
    const float* gbhh  = (const float*)d_in[13];
    const float* lwih  = (const float*)d_in[14];
    const float* lwhh  = (const float*)d_in[15];
    const float* lbih  = (const float*)d_in[16];
    const float* lbhh  = (const float*)d_in[17];
    const float* fc1w  = (const float*)d_in[18];
    const float* fc1b  = (const float*)d_in[19];
    const float* fc2w  = (const float*)d_in[20];
    const float* fc2b  = (const float*)d_in[21];

    unsigned short* emsg = (unsigned short*)d_ws;        // [E,64] fp16 33.5MB
    float* buf  = (float*)(emsg + (size_t)N_EDGES * 64); // [N,64] 33.5MB
    int* deg    = (int*)(buf + (size_t)N_NODES * 64);    // [N]
    int* cursor = deg + N_NODES;                          // [N]
    int* rowp   = cursor + N_NODES;                       // [N+1]
    int* epos   = rowp + N_NODES + 1;                     // [E]
    int* psum   = epos + N_EDGES;                         // [512]
    int* psumx  = psum + 512;                             // [512]
    int* starts = psumx + 512;                            // [B+1]
    size_t off = (size_t)((char*)(starts + N_B + 1) - (char*)d_ws);
    off = (off + 15) & ~(size_t)15;
    unsigned short* wt  = (unsigned short*)((char*)d_ws + off);  // fp16 we2 frags
    unsigned short* wtg = wt + 262144;                            // GRU fp16 frags
    float* gbias = (float*)(wtg + 32768);                         // 256 floats
    float4* wA = (float4*)(gbias + 256);                          // 64KB
    float4* wB = wA + 4096;                                       // 64KB
    float* y = (float*)d_out;

    hipMemsetAsync(deg, 0, (size_t)N_NODES * sizeof(int), stream);
    k_misc<<<1129, 256, 0, stream>>>(we2, wt, gwih, gwhh, gbih, gbhh, wtg, gbias,
                                     lwih, lwhh, wA, wB, batch, starts, eidx, deg);
    k_scan1<<<512, 256, 0, stream>>>(deg, psum);
    k_scan2<<<1, 512, 0, stream>>>(psum, psumx);
    k_scan3<<<512, 256, 0, stream>>>(deg, psumx, rowp, cursor);
    k_scat<<<1024, 256, 0, stream>>>(eidx, cursor, epos);
    k_edge<<<N_EDGES / 128, 512, 0, stream>>>(x, ea, eidx, epos, we1, be1, wt, be2, emsg);
    k_gru2<<<N_NODES / 128, 256, 0, stream>>>(buf, emsg, rowp, x, root, cb,
                                              wtg, gbias);
    k_s2s<<<N_B / 4, 256, 0, stream>>>(buf, starts, wA, wB, lbih, lbhh,
                                       fc1w, fc1b, fc2w, fc2b, y);
}